// Round 5
// baseline (1445.923 us; speedup 1.0000x reference)
//
#include <hip/hip_runtime.h>
#include <hip/hip_bf16.h>

#define D 128
#define NV 100000
#define NB 2048
#define SS 8
#define NN (NB*SS)      // 16384
#define NE (NB*(SS-1))  // 14336
#define VPAD 100096     // 782*128
#define CBLK 782
#define LSCALE 12.0f

typedef __attribute__((ext_vector_type(4))) float f32x4;
typedef __attribute__((ext_vector_type(8))) short bf16x8;

__device__ inline float warp_sum64(float v){
  #pragma unroll
  for (int off=1; off<64; off<<=1) v += __shfl_xor(v, off, 64);
  return v;
}

// ---- feat = normalize(emb[iid], eps=1e-12), one wave per node ----
__global__ void k_feat(const int* __restrict__ iid, const float* __restrict__ emb,
                       float* __restrict__ feat){
  int node = blockIdx.x*4 + (threadIdx.x>>6);
  int l = threadIdx.x & 63;
  int idx = iid[node];
  float v0 = emb[(size_t)idx*D + l];
  float v1 = emb[(size_t)idx*D + 64 + l];
  float ss = warp_sum64(v0*v0 + v1*v1);
  float inv = 1.0f/(sqrtf(ss)+1e-12f);
  feat[node*D + l]      = v0*inv;
  feat[node*D + 64 + l] = v1*inv;
}

// ---- edge scatter: m1[dst]+=feat[src]*w, m2[src]+=feat[dst]*w ----
__global__ void k_scatter(const int* __restrict__ src, const int* __restrict__ dst,
                          const float* __restrict__ w, const float* __restrict__ feat,
                          float* __restrict__ m1, float* __restrict__ m2,
                          float* __restrict__ ws1, float* __restrict__ ws2){
  int e = blockIdx.x*2 + (threadIdx.x>>7);
  int d = threadIdx.x & 127;
  int s = src[e], dd = dst[e];
  float wt = w[e];
  atomicAdd(&m1[dd*D + d], feat[s*D + d]*wt);
  atomicAdd(&m2[s*D + d],  feat[dd*D + d]*wt);
  if (d==0){ atomicAdd(&ws1[dd], wt); atomicAdd(&ws2[s], wt); }
}

__global__ void k_neighdiv(float* __restrict__ m1, float* __restrict__ m2,
                           const float* __restrict__ ws1, const float* __restrict__ ws2){
  int i = blockIdx.x*256 + threadIdx.x;
  int n = i >> 7;
  float a = ws1[n], b = ws2[n];
  m1[i] = a>0.f ? m1[i]/a : 0.f;
  m2[i] = b>0.f ? m2[i]/b : 0.f;
}

// ---- generic fp32 GEMM: C[M,N] = A[M,K] @ W[N,K]^T (+bias), 64x64 tile ----
__global__ __launch_bounds__(256) void gemm_bt(
    const float* __restrict__ A, int lda,
    const float* __restrict__ W,
    const float* __restrict__ bias,
    float* __restrict__ C, int ldc, int K)
{
  __shared__ float As[16][65];
  __shared__ float Ws[16][65];
  int tid = threadIdx.x;
  int tx = tid & 15, ty = tid >> 4;
  int row0 = blockIdx.y*64, col0 = blockIdx.x*64;
  int r = tid >> 2, c4 = (tid & 3)*4;
  float acc[4][4] = {};
  for (int k0=0;k0<K;k0+=16){
    float4 a  = *(const float4*)&A[(size_t)(row0+r)*lda + k0 + c4];
    float4 wv = *(const float4*)&W[(size_t)(col0+r)*K  + k0 + c4];
    As[c4+0][r]=a.x;  As[c4+1][r]=a.y;  As[c4+2][r]=a.z;  As[c4+3][r]=a.w;
    Ws[c4+0][r]=wv.x; Ws[c4+1][r]=wv.y; Ws[c4+2][r]=wv.z; Ws[c4+3][r]=wv.w;
    __syncthreads();
    #pragma unroll
    for (int kk=0;kk<16;kk++){
      float ar[4], wr[4];
      #pragma unroll
      for (int i=0;i<4;i++) ar[i]=As[kk][ty*4+i];
      #pragma unroll
      for (int j=0;j<4;j++) wr[j]=Ws[kk][tx*4+j];
      #pragma unroll
      for (int i=0;i<4;i++)
        #pragma unroll
        for (int j=0;j<4;j++) acc[i][j] += ar[i]*wr[j];
    }
    __syncthreads();
  }
  #pragma unroll
  for (int i=0;i<4;i++){
    int rr = row0+ty*4+i;
    #pragma unroll
    for (int j=0;j<4;j++){
      int cc = col0+tx*4+j;
      float v = acc[i][j] + (bias ? bias[cc] : 0.f);
      C[(size_t)rr*ldc + cc] = v;
    }
  }
}

// ---- GRU cell + concat + L2 normalize -> feat2 [N,256], one wave per node ----
__global__ void k_gru(const float* __restrict__ gi, const float* __restrict__ gh,
                      const float* __restrict__ feat, float* __restrict__ feat2){
  int node = blockIdx.x*4 + (threadIdx.x>>6);
  int l = threadIdx.x & 63;
  float o[2], f[2];
  float ss = 0.f;
  #pragma unroll
  for (int h=0;h<2;h++){
    int d = l + h*64;
    float ir = gi[node*384 + d], iz = gi[node*384 + 128 + d], in_ = gi[node*384 + 256 + d];
    float hr = gh[node*384 + d], hz = gh[node*384 + 128 + d], hn  = gh[node*384 + 256 + d];
    float rg = 1.f/(1.f+__expf(-(ir+hr)));
    float zg = 1.f/(1.f+__expf(-(iz+hz)));
    float ng = tanhf(in_ + rg*hn);
    float fd = feat[node*D + d];
    float od = (1.f-zg)*ng + zg*fd;
    o[h]=od; f[h]=fd;
    ss += od*od + fd*fd;
  }
  ss = warp_sum64(ss);
  float inv = 1.f/sqrtf(ss);   // reference: no eps here
  feat2[node*256 + l]       = o[0]*inv;
  feat2[node*256 + 64 + l]  = o[1]*inv;
  feat2[node*256 + 128 + l] = f[0]*inv;
  feat2[node*256 + 192 + l] = f[1]*inv;
}

__global__ void k_gather(const int* __restrict__ last_nodes, const float* __restrict__ feat2,
                         float* __restrict__ srcat){
  int b = blockIdx.x, d = threadIdx.x;
  srcat[b*384 + d] = feat2[last_nodes[b]*256 + d];
}

// ---- e[n] = sigmoid(fu[n]+fv[seg[n]]) . We ----
__global__ void k_escore(const float* __restrict__ fu, const float* __restrict__ fv,
                         const int* __restrict__ node_seg, const float* __restrict__ We,
                         float* __restrict__ evec){
  int node = blockIdx.x*4 + (threadIdx.x>>6);
  int l = threadIdx.x & 63;
  int seg = node_seg[node];
  float s = 0.f;
  #pragma unroll
  for (int h=0;h<2;h++){
    int d = l + h*64;
    float x = fu[node*D + d] + fv[seg*D + d];
    s += (1.f/(1.f+__expf(-x))) * We[d];
  }
  s = warp_sum64(s);
  if (l==0) evec[node]=s;
}

// ---- per-session softmax over 8 nodes + weighted pooling -> sg [B,256] ----
__global__ void k_attnpool(const float* __restrict__ evec, const float* __restrict__ feat2,
                           float* __restrict__ sg){
  __shared__ float ev[SS];
  int b = blockIdx.x, t = threadIdx.x;
  if (t < SS) ev[t] = evec[b*SS + t];
  __syncthreads();
  float m = ev[0];
  #pragma unroll
  for (int s=1;s<SS;s++) m = fmaxf(m, ev[s]);
  float al[SS]; float se = 0.f;
  #pragma unroll
  for (int s=0;s<SS;s++){ al[s] = __expf(ev[s]-m); se += al[s]; }
  float inv = 1.f/se;
  float acc = 0.f;
  #pragma unroll
  for (int s=0;s<SS;s++) acc += feat2[(b*SS+s)*256 + t] * (al[s]*inv);
  sg[b*256 + t] = acc;
}

__global__ void k_srnorm(const float* __restrict__ srb, __hip_bfloat16* __restrict__ srbf){
  int b = blockIdx.x*4 + (threadIdx.x>>6);
  int l = threadIdx.x & 63;
  float v0 = srb[b*D + l], v1 = srb[b*D + 64 + l];
  float ss = warp_sum64(v0*v0 + v1*v1);
  float inv = 1.f/(sqrtf(ss)+1e-12f);
  srbf[b*D + l]      = __float2bfloat16(v0*inv);
  srbf[b*D + 64 + l] = __float2bfloat16(v1*inv);
}

__global__ void k_tgtnorm(const float* __restrict__ emb, __hip_bfloat16* __restrict__ tgt){
  int v = blockIdx.x*4 + (threadIdx.x>>6);
  int l = threadIdx.x & 63;
  float a=0.f, b=0.f;
  if (v < NV){ a = emb[(size_t)v*D + l]; b = emb[(size_t)v*D + 64 + l]; }
  float ss = warp_sum64(a*a + b*b);
  float inv = 1.f/(sqrtf(ss)+1e-12f);
  tgt[(size_t)v*D + l]      = __float2bfloat16(a*inv);
  tgt[(size_t)v*D + 64 + l] = __float2bfloat16(b*inv);
}

// ---- big matmul sr @ tgt^T (bf16 MFMA), pass1: row sumexp, pass2: write out ----
__global__ __launch_bounds__(256) void k_logits(
    const __hip_bfloat16* __restrict__ Abf,
    const __hip_bfloat16* __restrict__ Bbf,
    const float* __restrict__ lse,
    float* __restrict__ psum,
    float* __restrict__ out,
    int pass)
{
  __shared__ ushort As[128][136];   // +8 pad: balanced banks for b128 frag reads
  __shared__ ushort Bs[128][136];
  __shared__ float rowsum[2][128];
  int tid = threadIdx.x;
  int rowblk = blockIdx.y, colblk = blockIdx.x;
  const ushort* Au = (const ushort*)Abf;
  const ushort* Bu = (const ushort*)Bbf;
  #pragma unroll
  for (int t=0;t<8;t++){
    int c = t*256 + tid;
    int rr = c >> 4, c16 = (c & 15)*8;
    *(bf16x8*)&As[rr][c16] = *(const bf16x8*)&Au[(size_t)(rowblk*128+rr)*D + c16];
    *(bf16x8*)&Bs[rr][c16] = *(const bf16x8*)&Bu[(size_t)(colblk*128+rr)*D + c16];
  }
  __syncthreads();
  int wid = tid>>6, lane = tid&63;
  int wr = wid>>1, wc = wid&1;
  int g = lane>>4, lr = lane&15;
  f32x4 acc[4][4];
  #pragma unroll
  for (int m=0;m<4;m++)
    #pragma unroll
    for (int n=0;n<4;n++) acc[m][n] = (f32x4){0.f,0.f,0.f,0.f};
  #pragma unroll
  for (int ks=0; ks<4; ks++){
    bf16x8 af[4], bfr[4];
    #pragma unroll
    for (int m=0;m<4;m++) af[m]  = *(bf16x8*)&As[wr*64+m*16+lr][ks*32+g*8];
    #pragma unroll
    for (int n=0;n<4;n++) bfr[n] = *(bf16x8*)&Bs[wc*64+n*16+lr][ks*32+g*8];
    #pragma unroll
    for (int m=0;m<4;m++)
      #pragma unroll
      for (int n=0;n<4;n++)
        acc[m][n] = __builtin_amdgcn_mfma_f32_16x16x32_bf16(af[m], bfr[n], acc[m][n], 0,0,0);
  }
  if (pass==1){
    float s[4][4];
    #pragma unroll
    for (int m=0;m<4;m++)
      #pragma unroll
      for (int i=0;i<4;i++) s[m][i]=0.f;
    #pragma unroll
    for (int m=0;m<4;m++)
      #pragma unroll
      for (int n=0;n<4;n++){
        int col = colblk*128 + wc*64 + n*16 + lr;
        #pragma unroll
        for (int i=0;i<4;i++){
          float v = (col < NV) ? __expf(LSCALE*acc[m][n][i]) : 0.f;
          s[m][i] += v;
        }
      }
    #pragma unroll
    for (int off=1; off<16; off<<=1)
      #pragma unroll
      for (int m=0;m<4;m++)
        #pragma unroll
        for (int i=0;i<4;i++) s[m][i] += __shfl_xor(s[m][i], off, 64);
    if (lr==0){
      #pragma unroll
      for (int m=0;m<4;m++)
        #pragma unroll
        for (int i=0;i<4;i++) rowsum[wc][wr*64 + m*16 + g*4 + i] = s[m][i];
    }
    __syncthreads();
    if (tid < 128)
      psum[(size_t)colblk*NB + rowblk*128 + tid] = rowsum[0][tid] + rowsum[1][tid];
  } else {
    #pragma unroll
    for (int m=0;m<4;m++)
      #pragma unroll
      for (int i=0;i<4;i++){
        int row = rowblk*128 + wr*64 + m*16 + g*4 + i;
        float L = lse[row];
        #pragma unroll
        for (int n=0;n<4;n++){
          int col = colblk*128 + wc*64 + n*16 + lr;
          if (col < NV) out[(size_t)row*NV + col] = LSCALE*acc[m][n][i] - L;
        }
      }
  }
}

__global__ void k_lse(const float* __restrict__ psum, float* __restrict__ lse){
  int row = blockIdx.x*256 + threadIdx.x;
  float s=0.f;
  for (int cb=0;cb<CBLK;cb++) s += psum[(size_t)cb*NB + row];
  lse[row] = logf(s);
}

extern "C" void kernel_launch(void* const* d_in, const int* in_sizes, int n_in,
                              void* d_out, int out_size, void* d_ws, size_t ws_size,
                              hipStream_t stream) {
  const int*   iid        = (const int*)d_in[0];
  const int*   src        = (const int*)d_in[1];
  const int*   dst        = (const int*)d_in[2];
  const int*   node_seg   = (const int*)d_in[3];
  const int*   last_nodes = (const int*)d_in[4];
  const float* w          = (const float*)d_in[5];
  const float* emb        = (const float*)d_in[6];
  const float* W1         = (const float*)d_in[7];
  const float* W2         = (const float*)d_in[8];
  const float* W_ih       = (const float*)d_in[9];
  const float* W_hh       = (const float*)d_in[10];
  const float* b_ih       = (const float*)d_in[11];
  const float* b_hh       = (const float*)d_in[12];
  const float* Wu         = (const float*)d_in[13];
  const float* Wv         = (const float*)d_in[14];
  const float* bv         = (const float*)d_in[15];
  const float* We         = (const float*)d_in[16];
  const float* Wout       = (const float*)d_in[17];
  const float* Wsr        = (const float*)d_in[18];
  float* out = (float*)d_out;

  char* wsb = (char*)d_ws;
  size_t off = 0;
  auto alloc = [&](size_t bytes){ void* p = wsb + off; off += (bytes + 255) & ~(size_t)255; return p; };
  float* feat  = (float*)alloc((size_t)NN*D*4);
  float* m1    = (float*)alloc((size_t)NN*D*4);
  float* m2    = (float*)alloc((size_t)NN*D*4);
  float* ws1   = (float*)alloc((size_t)NN*4);
  float* ws2   = (float*)alloc((size_t)NN*4);
  float* xcat  = (float*)alloc((size_t)NN*256*4);
  float* gi    = (float*)alloc((size_t)NN*384*4);
  float* gh    = (float*)alloc((size_t)NN*384*4);
  float* feat2 = (float*)alloc((size_t)NN*256*4);
  float* fu    = (float*)alloc((size_t)NN*D*4);
  float* evec  = (float*)alloc((size_t)NN*4);
  float* srcat = (float*)alloc((size_t)NB*384*4);
  float* fv    = (float*)alloc((size_t)NB*D*4);
  float* sg    = (float*)alloc((size_t)NB*256*4);
  float* srb   = (float*)alloc((size_t)NB*D*4);
  __hip_bfloat16* srbf = (__hip_bfloat16*)alloc((size_t)NB*D*2);
  __hip_bfloat16* tgt  = (__hip_bfloat16*)alloc((size_t)VPAD*D*2);
  float* psum  = (float*)alloc((size_t)CBLK*NB*4);
  float* lse   = (float*)alloc((size_t)NB*4);

  // zero the atomic accumulators (m1,m2,ws1,ws2 are contiguous)
  hipMemsetAsync(m1, 0, ((size_t)2*NN*D + 2*NN)*4, stream);

  k_feat<<<NN/4, 256, 0, stream>>>(iid, emb, feat);
  k_scatter<<<NE/2, 256, 0, stream>>>(src, dst, w, feat, m1, m2, ws1, ws2);
  k_neighdiv<<<NN*D/256, 256, 0, stream>>>(m1, m2, ws1, ws2);
  gemm_bt<<<dim3(2, NN/64), 256, 0, stream>>>(m1, D, W1, nullptr, xcat, 256, D);        // n1
  gemm_bt<<<dim3(2, NN/64), 256, 0, stream>>>(m2, D, W2, nullptr, xcat+128, 256, D);    // n2
  gemm_bt<<<dim3(6, NN/64), 256, 0, stream>>>(xcat, 256, W_ih, b_ih, gi, 384, 256);     // gi
  gemm_bt<<<dim3(6, NN/64), 256, 0, stream>>>(feat, D, W_hh, b_hh, gh, 384, D);         // gh
  k_gru<<<NN/4, 256, 0, stream>>>(gi, gh, feat, feat2);
  gemm_bt<<<dim3(2, NN/64), 256, 0, stream>>>(feat2, 256, Wu, nullptr, fu, D, 256);     // fu
  k_gather<<<NB, 256, 0, stream>>>(last_nodes, feat2, srcat);
  gemm_bt<<<dim3(2, NB/64), 256, 0, stream>>>(srcat, 384, Wv, bv, fv, D, 256);          // fv
  k_escore<<<NN/4, 256, 0, stream>>>(fu, fv, node_seg, We, evec);
  k_attnpool<<<NB, 256, 0, stream>>>(evec, feat2, sg);
  gemm_bt<<<dim3(2, NB/64), 256, 0, stream>>>(sg, 256, Wout, nullptr, srcat+256, 384, 256); // sr_g
  gemm_bt<<<dim3(2, NB/64), 256, 0, stream>>>(srcat, 384, Wsr, nullptr, srb, D, 384);   // sr
  k_srnorm<<<NB/4, 256, 0, stream>>>(srb, srbf);
  k_tgtnorm<<<VPAD/4, 256, 0, stream>>>(emb, tgt);
  k_logits<<<dim3(CBLK, NB/128), 256, 0, stream>>>(srbf, tgt, nullptr, psum, nullptr, 1);
  k_lse<<<NB/256, 256, 0, stream>>>(psum, lse);
  k_logits<<<dim3(CBLK, NB/128), 256, 0, stream>>>(srbf, tgt, lse, nullptr, out, 2);
}